// Round 5
// baseline (631.904 us; speedup 1.0000x reference)
//
#include <hip/hip_runtime.h>
#include <hip/hip_fp16.h>

#define BB 8
#define CC 3
#define HH 720
#define WW 1280
#define PLANE (HH*WW)
#define NPIX (BB*HH*WW)

#define PXX 64              // output tile width per block
#define PYY 16              // output tile height per block
#define RAD 3               // regular iff flow in [-3,3) per axis
#define NBX (WW/PXX)        // 20
#define NBY (HH/PYY)        // 45
#define WINX (PXX+2*RAD)    // 70 source-window cols
#define WINY (PYY+2*RAD)    // 22 source-window rows
#define NWIN (WINX*WINY)    // 1540
#define CX 65               // corner cells x: x0 in [X0-1, X0+63]
#define CY 17               // corner cells y: y0 in [Y0-1, Y0+15]
#define NCELL (CX*CY)       // 1105
#define DEPTH 4

// LDS layout in dwords: FXY | V01 | V2(half) | CNT  = 48620 bytes
#define OFF_FXY 0
#define OFF_V01 (NCELL*DEPTH)                    // 4420
#define OFF_V2  (2*NCELL*DEPTH)                  // 8840
#define OFF_CNT (2*NCELL*DEPTH + NCELL*DEPTH/2)  // 11050
#define LDS_DW  (OFF_CNT + NCELL)                // 12155

static __device__ __forceinline__ float h2f_lo(unsigned int u) {
    return __half2float(__ushort_as_half((unsigned short)(u & 0xffffu)));
}
static __device__ __forceinline__ float h2f_hi(unsigned int u) {
    return __half2float(__ushort_as_half((unsigned short)(u >> 16)));
}

// ---------------------------------------------------------------------------
// main kernel: bucket records by corner cell in LDS, then direct 4-cell gather
// ---------------------------------------------------------------------------
__global__ __launch_bounds__(256) void fw_gather(
    const float* __restrict__ im0,
    const float* __restrict__ flow,
    float* __restrict__ out,
    unsigned int* __restrict__ ovf_cnt,
    float* __restrict__ ovf_rec,      // 6 floats per record
    unsigned int ovf_cap)
{
    __shared__ __align__(16) unsigned int lds[LDS_DW];
    unsigned int* FXY = lds + OFF_FXY;
    unsigned int* V01 = lds + OFF_V01;
    unsigned short* V2h = (unsigned short*)(lds + OFF_V2);
    unsigned int* CNT = lds + OFF_CNT;

    const int bx = blockIdx.x, by = blockIdx.y, b = blockIdx.z;
    const int X0 = bx * PXX, Y0 = by * PYY;
    const int tid = threadIdx.x;

    // zero everything (zero records contribute wt*0 = 0; fx=0 gives finite wts)
    for (int i = tid; i < LDS_DW; i += 256) lds[i] = 0u;
    __syncthreads();

    // ---- phase A: bucket source records by their corner cell ----
    for (int i = tid; i < NWIN; i += 256) {
        int wy = i / WINX;
        int wx = i - wy * WINX;
        int gx = X0 - RAD + wx;
        int gy = Y0 - RAD + wy;
        if (gx < 0 || gx >= WW || gy < 0 || gy >= HH) continue;
        float2 f = reinterpret_cast<const float2*>(flow)[(b * HH + gy) * WW + gx];
        bool reg = (f.x >= -(float)RAD) & (f.x < (float)RAD)
                 & (f.y >= -(float)RAD) & (f.y < (float)RAD);
        if (reg) {
            float x = (float)gx + f.x;       // same op order as reference
            float y = (float)gy + f.y;
            float x0f = floorf(x), y0f = floorf(y);
            int cx = (int)x0f - (X0 - 1);
            int cy = (int)y0f - (Y0 - 1);
            if (cx >= 0 && cx < CX && cy >= 0 && cy < CY) {
                int src = b * CC * PLANE + gy * WW + gx;
                float v0 = im0[src];
                float v1 = im0[src + PLANE];
                float v2 = im0[src + 2 * PLANE];
                float fx = x - x0f, fy = y - y0f;
                int cell = cy * CX + cx;
                unsigned int slot = atomicAdd(&CNT[cell], 1u);
                if (slot < DEPTH) {
                    int o = cell * DEPTH + slot;
                    FXY[o] = (unsigned int)__half_as_ushort(__float2half(fx))
                           | ((unsigned int)__half_as_ushort(__float2half(fy)) << 16);
                    V01[o] = (unsigned int)__half_as_ushort(__float2half(v0))
                           | ((unsigned int)__half_as_ushort(__float2half(v1)) << 16);
                    V2h[o] = __half_as_ushort(__float2half(v2));
                } else {
                    // depth overflow (rare): list for owner-clipped replay (type 1)
                    unsigned int s2 = atomicAdd(ovf_cnt, 1u);
                    if (s2 < ovf_cap) {
                        float* q = ovf_rec + (size_t)s2 * 6;
                        q[0] = __int_as_float(b | (bx << 4) | (by << 9) | (1 << 15));
                        q[1] = x; q[2] = y;
                        q[3] = v0; q[4] = v1; q[5] = v2;
                    }
                }
            }
        } else if (wx >= RAD && wx < RAD + PXX && wy >= RAD && wy < RAD + PYY) {
            // irregular flow, core-owned pixel: full-splat replay (type 0)
            int src = b * CC * PLANE + gy * WW + gx;
            unsigned int s2 = atomicAdd(ovf_cnt, 1u);
            if (s2 < ovf_cap) {
                float* q = ovf_rec + (size_t)s2 * 6;
                q[0] = __int_as_float(b | (bx << 4) | (by << 9));
                q[1] = (float)gx + f.x; q[2] = (float)gy + f.y;
                q[3] = im0[src]; q[4] = im0[src + PLANE]; q[5] = im0[src + 2 * PLANE];
            }
        }
    }
    __syncthreads();

    // ---- phase B: each thread gathers 4 outputs from 10 cells, no testing ----
    const int lane = tid & 63;
    const int rg = tid >> 6;                   // 0..3
    const int X = X0 + lane;
    const int Ybase = Y0 + rg * 4;

    float a0[4] = {0.f, 0.f, 0.f, 0.f};
    float a1[4] = {0.f, 0.f, 0.f, 0.f};
    float a2[4] = {0.f, 0.f, 0.f, 0.f};

#pragma unroll
    for (int r = 0; r < 5; ++r) {              // cell rows y0 = Ybase-1+r
        const int cy = rg * 4 + r;
#pragma unroll
        for (int side = 0; side < 2; ++side) { // side0: x0=X-1 (wx=fx); side1: x0=X (wx=1-fx)
            const int cell = (cy * CX + lane + side) * DEPTH;
            uint4 fxy4 = *reinterpret_cast<const uint4*>(&FXY[cell]);
            uint4 v014 = *reinterpret_cast<const uint4*>(&V01[cell]);
            ushort4 v24 = *reinterpret_cast<const ushort4*>(&V2h[cell]);
            unsigned int fxys[4] = {fxy4.x, fxy4.y, fxy4.z, fxy4.w};
            unsigned int v01s[4] = {v014.x, v014.y, v014.z, v014.w};
            unsigned short v2s[4] = {v24.x, v24.y, v24.z, v24.w};
#pragma unroll
            for (int k = 0; k < DEPTH; ++k) {
                float fx = h2f_lo(fxys[k]);
                float fy = h2f_hi(fxys[k]);
                float v0 = h2f_lo(v01s[k]);
                float v1 = h2f_hi(v01s[k]);
                float v2 = __half2float(__ushort_as_half(v2s[k]));
                float wx = side ? (1.0f - fx) : fx;
                float wv0 = wx * v0, wv1 = wx * v1, wv2 = wx * v2;
                if (r >= 1) {                  // output j = r-1, weight 1-fy
                    float wy = 1.0f - fy;
                    a0[r-1] += wy * wv0; a1[r-1] += wy * wv1; a2[r-1] += wy * wv2;
                }
                if (r <= 3) {                  // output j = r, weight fy
                    a0[r] += fy * wv0; a1[r] += fy * wv1; a2[r] += fy * wv2;
                }
            }
        }
    }

#pragma unroll
    for (int j = 0; j < 4; ++j) {
        size_t o = (size_t)(b * CC) * PLANE + (size_t)(Ybase + j) * WW + X;
        out[o] = a0[j];
        out[o + PLANE] = a1[j];
        out[o + 2 * PLANE] = a2[j];
    }
}

// ---------------------------------------------------------------------------
// replay: type0 = irregular (full splat), type1 = depth overflow (owner-clipped)
// ---------------------------------------------------------------------------
__global__ void fw_overflow(const unsigned int* __restrict__ ovf_cnt,
                            const float* __restrict__ ovf_rec,
                            unsigned int ovf_cap,
                            float* __restrict__ out)
{
    unsigned int n = *ovf_cnt;
    if (n > ovf_cap) n = ovf_cap;
    for (unsigned int i = blockIdx.x * blockDim.x + threadIdx.x; i < n;
         i += gridDim.x * blockDim.x) {
        const float* q = ovf_rec + (size_t)i * 6;
        unsigned int meta = __float_as_uint(q[0]);
        int b   = meta & 0xf;
        int rx0 = ((meta >> 4) & 0x1f) * PXX;
        int ry0 = ((meta >> 9) & 0x3f) * PYY;
        int typ = (meta >> 15) & 1;
        float x = q[1], y = q[2];
        float v0 = q[3], v1 = q[4], v2 = q[5];
        float x0f = floorf(x), y0f = floorf(y);
        int x0 = (int)x0f, y0 = (int)y0f;
        float wx1 = x - x0f, wx0 = 1.0f - wx1;
        float wy1 = y - y0f, wy0 = 1.0f - wy1;
#pragma unroll
        for (int dy = 0; dy < 2; ++dy) {
            int yi = y0 + dy;
            float wy = dy ? wy1 : wy0;
#pragma unroll
            for (int dx = 0; dx < 2; ++dx) {
                int xi = x0 + dx;
                bool valid = (xi >= 0) && (xi < WW) && (yi >= 0) && (yi < HH);
                if (typ)
                    valid = valid && (xi >= rx0) && (xi < rx0 + PXX)
                                  && (yi >= ry0) && (yi < ry0 + PYY);
                if (valid) {
                    float wt = wy * (dx ? wx1 : wx0);
                    int o = b * CC * PLANE + yi * WW + xi;
                    unsafeAtomicAdd(&out[o],             wt * v0);
                    unsafeAtomicAdd(&out[o + PLANE],     wt * v1);
                    unsafeAtomicAdd(&out[o + 2 * PLANE], wt * v2);
                }
            }
        }
    }
}

// ---------------------------------------------------------------------------
// safety fallback (tiny ws): naive global-atomic splat
// ---------------------------------------------------------------------------
__global__ __launch_bounds__(256) void fw_naive(
    const float* __restrict__ im0,
    const float* __restrict__ flow,
    float* __restrict__ out)
{
    int idx = blockIdx.x * blockDim.x + threadIdx.x;
    if (idx >= NPIX) return;
    int w = idx % WW;
    int t = idx / WW;
    int h = t % HH;
    int b = t / HH;
    float2 f = reinterpret_cast<const float2*>(flow)[idx];
    float x = (float)w + f.x, y = (float)h + f.y;
    float x0f = floorf(x), y0f = floorf(y);
    int x0 = (int)x0f, y0 = (int)y0f;
    float wx1 = x - x0f, wx0 = 1.0f - wx1;
    float wy1 = y - y0f, wy0 = 1.0f - wy1;
    int src = (b * CC * HH + h) * WW + w;
    float v0 = im0[src], v1 = im0[src + PLANE], v2 = im0[src + 2 * PLANE];
#pragma unroll
    for (int dy = 0; dy < 2; ++dy) {
        int yi = y0 + dy;
        if (yi < 0 || yi >= HH) continue;
        float wy = dy ? wy1 : wy0;
#pragma unroll
        for (int dx = 0; dx < 2; ++dx) {
            int xi = x0 + dx;
            if (xi < 0 || xi >= WW) continue;
            float wt = wy * (dx ? wx1 : wx0);
            int o = (b * CC) * PLANE + yi * WW + xi;
            unsafeAtomicAdd(&out[o],             wt * v0);
            unsafeAtomicAdd(&out[o + PLANE],     wt * v1);
            unsafeAtomicAdd(&out[o + 2 * PLANE], wt * v2);
        }
    }
}

extern "C" void kernel_launch(void* const* d_in, const int* in_sizes, int n_in,
                              void* d_out, int out_size, void* d_ws, size_t ws_size,
                              hipStream_t stream)
{
    const float* im0  = (const float*)d_in[0];
    const float* flow = (const float*)d_in[1];
    float* out = (float*)d_out;

    const size_t rec_off = 256;
    if (ws_size >= rec_off + (size_t)262144 * 24) {   // >= ~6.3 MB for records
        unsigned int* cnt = (unsigned int*)d_ws;
        float* rec = (float*)((char*)d_ws + rec_off);
        unsigned int cap = (unsigned int)((ws_size - rec_off) / 24);

        hipMemsetAsync(cnt, 0, 256, stream);
        dim3 g(NBX, NBY, BB);     // 20 x 45 x 8
        fw_gather<<<g, 256, 0, stream>>>(im0, flow, out, cnt, rec, cap);
        fw_overflow<<<64, 256, 0, stream>>>(cnt, rec, cap, out);
    } else {
        hipMemsetAsync(out, 0, (size_t)out_size * sizeof(float), stream);
        fw_naive<<<(NPIX + 255) / 256, 256, 0, stream>>>(im0, flow, out);
    }
}